// Round 4
// baseline (334.130 us; speedup 1.0000x reference)
//
#include <hip/hip_runtime.h>
#include <stdint.h>

// SobelLoss: mean over 3 dirs of mean |sobel(moved) - sobel(label)|.
// conv(m)-conv(l) = conv(m-l); separable: s=[1,2,1], d=[-1,0,1]:
//   gx = sD*sH*dW, gy = sD*dH*sW, gz = -dD*sH*sW.
// R4: exact 400-quad DMA staging (R3 overshot 12% + clamped OOB fetches),
// 2-slot pipeline (barrier drains vmcnt(0) anyway -> depth-1 prefetch; 3rd
// slot only cost LDS), DC=5 -> 1536 blocks = 6 blocks/CU, 24 waves/CU.
// NOTE (R2 lesson): never hold prefetched data in VGPRs across the plane
// barrier here — it spills (198 MB scratch traffic). DMA straight to LDS.

#define BB 2
#define DD 160
#define HH 192
#define WW 160
#define HW (HH * WW)

#define TH 8                    // H rows per block
#define DC 5                    // D slices per block
#define NIT (DC + 2)            // 7
#define PROWS (TH + 2)          // 10
#define PFLOATS (PROWS * WW)    // 1600 floats per plane tile (one 6400B span)
#define NQUADS (PFLOATS / 4)    // 400
#define NTHREADS 256
#define WPT 5                   // 32 w-groups * 5 = 160

#define AS1 __attribute__((address_space(1)))
#define AS3 __attribute__((address_space(3)))

__device__ __forceinline__ void dma16(const float* g, float* l) {
    __builtin_amdgcn_global_load_lds((const AS1 void*)g, (AS3 void*)l, 16, 0, 0);
}

__global__ __launch_bounds__(NTHREADS, 6) void sobel_loss_kernel(
    const float* __restrict__ moved, const float* __restrict__ label,
    float* __restrict__ out)
{
    __shared__ float sm[2][PFLOATS];   // raw moved planes
    __shared__ float sl[2][PFLOATS];   // raw label planes
    __shared__ float red[NTHREADS / 64];

    const int tid = threadIdx.x;
    const int h0  = blockIdx.x * TH;   // 24 tiles
    const int d0  = blockIdx.y * DC;   // 32 chunks
    const int b   = blockIdx.z;        // 2
    const int base_b = b * (DD * HW);

    // ---- DMA descriptors: quad q0 = tid (all), q1 = tid+256 (tid<144) ----
    const int q1 = tid + NTHREADS;
    // row of each quad (q/40), global row, validity: skip (not clamp) OOB rows
    const int gr0 = h0 - 1 + tid / 40;
    const int gr1 = h0 - 1 + q1 / 40;
    const bool hv0 = (unsigned)gr0 < (unsigned)HH;
    const bool hv1 = (q1 < NQUADS) && ((unsigned)gr1 < (unsigned)HH);

    // stage plane pl into slot s; tile is one contiguous span (full-W rows)
    auto stage = [&](int pl, int s) {
        if ((unsigned)pl >= (unsigned)DD) return;   // masked in compute
        const int pstart = base_b + pl * HW + (h0 - 1) * WW;
        if (hv0) { dma16(moved + pstart + tid * 4, &sm[s][tid * 4]);
                   dma16(label + pstart + tid * 4, &sl[s][tid * 4]); }
        if (hv1) { dma16(moved + pstart + q1 * 4, &sm[s][q1 * 4]);
                   dma16(label + pstart + q1 * 4, &sl[s][q1 * 4]); }
    };

    // ---- compute mapping: 8 h-rows x 32 w-groups of 5 ----
    const int hl    = tid >> 5;
    const int wbase = (tid & 31) * WPT;
    const bool rv0 = (h0 + hl) > 0;          // row gh = h0+hl-1 valid
    const bool rv2 = (h0 + hl + 1) < HH;     // row gh = h0+hl+1 valid

    float pxm1[WPT], pxm2[WPT], pym1[WPT], pym2[WPT], pzm1[WPT], pzm2[WPT];
#pragma unroll
    for (int k = 0; k < WPT; ++k) {
        pxm1[k] = pxm2[k] = 0.f;
        pym1[k] = pym2[k] = 0.f;
        pzm1[k] = pzm2[k] = 0.f;
    }
    float acc = 0.f;

    stage(d0 - 1, 0);
    __syncthreads();               // drain: plane d0-1 landed in slot 0

    for (int it = 0; it < NIT; ++it) {
        // issue next plane's DMA; flies during compute, drained at barrier.
        // 2-slot safety: slot (it+1)&1 was last READ at iter it-1, whose
        // readers passed the barrier at end of it-1, before this issue.
        if (it + 1 < NIT) stage(d0 + it, (it + 1) & 1);

        const int s = it & 1;
        const float* mb = sm[s];
        const float* lb = sl[s];
        const bool pv = (unsigned)(d0 - 1 + it) < (unsigned)DD;  // block-uniform

        const bool v0 = pv && rv0;
        const bool v2 = pv && rv2;
        const int o0 = hl * WW;
        const int o1 = o0 + WW;
        const int o2 = o1 + WW;

        float cS[WPT + 2], cD[WPT + 2];
#pragma unroll
        for (int x = 0; x < WPT + 2; ++x) {
            const int w  = wbase - 1 + x;
            const bool wv = (unsigned)w < (unsigned)WW;
            const int wc = wv ? w : (w < 0 ? 0 : WW - 1);   // in-tile LDS index
            const float a  = (v0 && wv) ? (mb[o0 + wc] - lb[o0 + wc]) : 0.f;
            const float m  = (pv && wv) ? (mb[o1 + wc] - lb[o1 + wc]) : 0.f;
            const float c2 = (v2 && wv) ? (mb[o2 + wc] - lb[o2 + wc]) : 0.f;
            cS[x] = (a + c2) + 2.f * m;   // smooth over H
            cD[x] = c2 - a;               // deriv  over H
        }
#pragma unroll
        for (int k = 0; k < WPT; ++k) {
            const float px = cS[k + 2] - cS[k];                     // dW sH
            const float pz = (cS[k] + cS[k + 2]) + 2.f * cS[k + 1]; // sW sH
            const float py = (cD[k] + cD[k + 2]) + 2.f * cD[k + 1]; // sW dH
            if (it >= 2) {
                const float gx = pxm2[k] + 2.f * pxm1[k] + px;  // sD
                const float gy = pym2[k] + 2.f * pym1[k] + py;  // sD
                const float gz = pzm2[k] - pz;                  // dD
                acc += fabsf(gx) + fabsf(gy) + fabsf(gz);
            }
            pxm2[k] = pxm1[k]; pxm1[k] = px;
            pym2[k] = pym1[k]; pym1[k] = py;
            pzm2[k] = pzm1[k]; pzm1[k] = pz;
        }

        __syncthreads();   // drains this iter's DMA; protects slot reuse
    }

    // ---- reduce: wave shuffle -> LDS -> one atomic per block ----
#pragma unroll
    for (int off = 32; off > 0; off >>= 1)
        acc += __shfl_down(acc, off, 64);
    if ((tid & 63) == 0) red[tid >> 6] = acc;
    __syncthreads();
    if (tid == 0) {
        const float s = red[0] + red[1] + red[2] + red[3];
        atomicAdd(out, s * (1.0f / (3.0f * BB * DD * HH * WW)));
    }
}

extern "C" void kernel_launch(void* const* d_in, const int* in_sizes, int n_in,
                              void* d_out, int out_size, void* d_ws, size_t ws_size,
                              hipStream_t stream) {
    const float* moved = (const float*)d_in[0];
    const float* label = (const float*)d_in[1];
    float* out = (float*)d_out;
    (void)in_sizes; (void)n_in; (void)out_size; (void)d_ws; (void)ws_size;

    hipMemsetAsync(out, 0, sizeof(float), stream);
    dim3 grid(HH / TH, DD / DC, BB);    // 24 x 32 x 2 = 1536 blocks (6/CU)
    sobel_loss_kernel<<<grid, NTHREADS, 0, stream>>>(moved, label, out);
}

// Round 5
// 130.000 us; speedup vs baseline: 2.5702x; 2.5702x over previous
//
#include <hip/hip_runtime.h>
#include <stdint.h>

// SobelLoss: mean over 3 dirs of mean |sobel(moved) - sobel(label)|.
// conv(m)-conv(l) = conv(m-l); separable: s=[1,2,1], d=[-1,0,1]:
//   gx = sD*sH*dW, gy = sD*dH*sW, gz = -dD*sH*sW.
// R5 = R3's staging (always-issue clamped DMA, wave-uniform exec) +
//      2 LDS slots (vmcnt(0) drain at barrier => depth-1 prefetch; 3rd slot
//      only cost occupancy) + DC=5 (1536 blocks, ~6 blocks/CU).
// HARD-WON RULES:
//  - NO __launch_bounds__ min-waves clamp: R2/R4 both spilled the 30-float
//    rolling window to scratch (200-480 MB HBM write traffic, 2-4x slower).
//  - global_load_lds predicates must be WAVE-UNIFORM (R4's per-lane `if`
//    serialized); clamp addresses instead, mask values at compute time.
//  - Never hold prefetched data in VGPRs across the barrier (R2 spill).

#define BB 2
#define DD 160
#define HH 192
#define WW 160
#define HW (HH * WW)
#define NTOT (BB * DD * HW)

#define TH 8                    // H rows per block
#define DC 5                    // D slices per block
#define NIT (DC + 2)            // 7
#define PROWS (TH + 2)          // 10
#define PFLOATS (PROWS * WW)    // 1600 floats per plane tile
#define PPAD 1792               // 448 quads = 256 + 192 (wave-uniform rounds)
#define NQUADS 448
#define NTHREADS 256
#define WPT 5                   // 32 w-groups * 5 = 160

#define AS1 __attribute__((address_space(1)))
#define AS3 __attribute__((address_space(3)))

__device__ __forceinline__ void dma16(const float* g, float* l) {
    __builtin_amdgcn_global_load_lds((const AS1 void*)g, (AS3 void*)l, 16, 0, 0);
}

__global__ __launch_bounds__(NTHREADS) void sobel_loss_kernel(
    const float* __restrict__ moved, const float* __restrict__ label,
    float* __restrict__ out)
{
    __shared__ float sm[2][PPAD];   // raw moved planes
    __shared__ float sl[2][PPAD];   // raw label planes
    __shared__ float red[NTHREADS / 64];

    const int tid = threadIdx.x;
    const int h0  = blockIdx.x * TH;   // 24 tiles
    const int d0  = blockIdx.y * DC;   // 32 chunks
    const int b   = blockIdx.z;        // 2
    const int base_b = b * (DD * HW);

    const bool do2 = (tid < 192);      // wave-uniform: waves 0..2 do 2nd quad

    // stage plane pl into slot s: always-issue, clamped addresses (uniform
    // exec); OOB rows/planes land garbage in LDS, masked at compute.
    auto stage = [&](int pl, int s) {
        if ((unsigned)pl >= (unsigned)DD) return;   // block-uniform
        const int pstart = base_b + pl * HW + (h0 - 1) * WW;
        int g0 = min(max(pstart + tid * 4, 0), NTOT - 4);
        dma16(moved + g0, &sm[s][tid * 4]);
        dma16(label + g0, &sl[s][tid * 4]);
        if (do2) {
            int g1 = min(max(pstart + (tid + NTHREADS) * 4, 0), NTOT - 4);
            dma16(moved + g1, &sm[s][(tid + NTHREADS) * 4]);
            dma16(label + g1, &sl[s][(tid + NTHREADS) * 4]);
        }
    };

    // ---- compute mapping: 8 h-rows x 32 w-groups of 5 ----
    const int hl    = tid >> 5;
    const int wbase = (tid & 31) * WPT;
    const bool rv0 = (h0 + hl) > 0;          // row gh = h0+hl-1 valid
    const bool rv2 = (h0 + hl + 1) < HH;     // row gh = h0+hl+1 valid

    float pxm1[WPT], pxm2[WPT], pym1[WPT], pym2[WPT], pzm1[WPT], pzm2[WPT];
#pragma unroll
    for (int k = 0; k < WPT; ++k) {
        pxm1[k] = pxm2[k] = 0.f;
        pym1[k] = pym2[k] = 0.f;
        pzm1[k] = pzm2[k] = 0.f;
    }
    float acc = 0.f;

    stage(d0 - 1, 0);
    __syncthreads();               // drain: plane d0-1 landed in slot 0

    for (int it = 0; it < NIT; ++it) {
        // issue next plane's DMA; flies during compute, drained at barrier.
        // 2-slot safety: slot (it+1)&1 was last READ at iter it-1, whose
        // readers passed the end-of-(it-1) barrier before this issue.
        if (it + 1 < NIT) stage(d0 + it, (it + 1) & 1);

        const int s = it & 1;
        const float* mb = sm[s];
        const float* lb = sl[s];
        const bool pv = (unsigned)(d0 - 1 + it) < (unsigned)DD;  // block-uniform

        const bool v0 = pv && rv0;
        const bool v2 = pv && rv2;
        const int o0 = hl * WW;
        const int o1 = o0 + WW;
        const int o2 = o1 + WW;

        float cS[WPT + 2], cD[WPT + 2];
#pragma unroll
        for (int x = 0; x < WPT + 2; ++x) {
            const int w  = wbase - 1 + x;
            const bool wv = (unsigned)w < (unsigned)WW;
            const int wc = wv ? w : (w < 0 ? 0 : WW - 1);   // in-tile LDS index
            const float a  = (v0 && wv) ? (mb[o0 + wc] - lb[o0 + wc]) : 0.f;
            const float m  = (pv && wv) ? (mb[o1 + wc] - lb[o1 + wc]) : 0.f;
            const float c2 = (v2 && wv) ? (mb[o2 + wc] - lb[o2 + wc]) : 0.f;
            cS[x] = (a + c2) + 2.f * m;   // smooth over H
            cD[x] = c2 - a;               // deriv  over H
        }
#pragma unroll
        for (int k = 0; k < WPT; ++k) {
            const float px = cS[k + 2] - cS[k];                     // dW sH
            const float pz = (cS[k] + cS[k + 2]) + 2.f * cS[k + 1]; // sW sH
            const float py = (cD[k] + cD[k + 2]) + 2.f * cD[k + 1]; // sW dH
            if (it >= 2) {
                const float gx = pxm2[k] + 2.f * pxm1[k] + px;  // sD
                const float gy = pym2[k] + 2.f * pym1[k] + py;  // sD
                const float gz = pzm2[k] - pz;                  // dD
                acc += fabsf(gx) + fabsf(gy) + fabsf(gz);
            }
            pxm2[k] = pxm1[k]; pxm1[k] = px;
            pym2[k] = pym1[k]; pym1[k] = py;
            pzm2[k] = pzm1[k]; pzm1[k] = pz;
        }

        __syncthreads();   // drains this iter's DMA; protects slot reuse
    }

    // ---- reduce: wave shuffle -> LDS -> one atomic per block ----
#pragma unroll
    for (int off = 32; off > 0; off >>= 1)
        acc += __shfl_down(acc, off, 64);
    if ((tid & 63) == 0) red[tid >> 6] = acc;
    __syncthreads();
    if (tid == 0) {
        const float s = red[0] + red[1] + red[2] + red[3];
        atomicAdd(out, s * (1.0f / (3.0f * BB * DD * HH * WW)));
    }
}

extern "C" void kernel_launch(void* const* d_in, const int* in_sizes, int n_in,
                              void* d_out, int out_size, void* d_ws, size_t ws_size,
                              hipStream_t stream) {
    const float* moved = (const float*)d_in[0];
    const float* label = (const float*)d_in[1];
    float* out = (float*)d_out;
    (void)in_sizes; (void)n_in; (void)out_size; (void)d_ws; (void)ws_size;

    hipMemsetAsync(out, 0, sizeof(float), stream);
    dim3 grid(HH / TH, DD / DC, BB);    // 24 x 32 x 2 = 1536 blocks
    sobel_loss_kernel<<<grid, NTHREADS, 0, stream>>>(moved, label, out);
}